// Round 1
// baseline (422.818 us; speedup 1.0000x reference)
//
#include <hip/hip_runtime.h>
#include <stdint.h>
#include <stddef.h>

// ---------------- types & helpers ----------------
typedef short s8v   __attribute__((ext_vector_type(8)));  // 8 bf16 in shorts (4 VGPRs)
typedef float f32x4 __attribute__((ext_vector_type(4)));

union BF8 { s8v v; unsigned short u[8]; };

__device__ __forceinline__ unsigned short bf16_rn(float x) {
  unsigned u = __builtin_bit_cast(unsigned, x);
  u += 0x7FFFu + ((u >> 16) & 1u);            // round-to-nearest-even
  return (unsigned short)(u >> 16);
}
__device__ __forceinline__ float bf16_f(unsigned short h) {
  unsigned u = ((unsigned)h) << 16;
  return __builtin_bit_cast(float, u);
}
__device__ __forceinline__ void split_f32(float x, unsigned short &h, unsigned short &l) {
  unsigned short hs = bf16_rn(x);
  h = hs;
  l = bf16_rn(x - bf16_f(hs));
}
__device__ __forceinline__ f32x4 mfma16(s8v a, s8v b, f32x4 c) {
  return __builtin_amdgcn_mfma_f32_16x16x32_bf16(a, b, c, 0, 0, 0);
}

// ---------------- problem sizes ----------------
#define BATCH 64
#define NN    4096
#define NX    128
#define NU    32
#define NY    32
// chunking: L=64 steps per chunk, 64 chunks per batch -> 4096 chains

// ---------------- workspace byte offsets ----------------
#define OFF_AH 0
#define OFF_AL 32768
#define OFF_BH 65536
#define OFF_BL 73728
#define OFF_CH 81920
#define OFF_CL 90112
#define OFF_DH 98304
#define OFF_DL 100352
#define OFF_GH 102400      // A^64 hi
#define OFF_GL 135168      // A^64 lo
#define OFF_P0 167936      // fp32 128x128 ping
#define OFF_P1 233472      // fp32 128x128 pong
#define OFF_V  299008      // v: 4096 x 128 fp32 (2 MB)
#define OFF_S  2396160     // s: 4096 x 128 fp32 (2 MB)
// total ~4.3 MB of d_ws

// ---------------- prep: split A,B,C,D into bf16 hi/lo ----------------
__global__ void k_convert(const float* __restrict__ A, const float* __restrict__ B,
                          const float* __restrict__ C, const float* __restrict__ D,
                          unsigned short* Ah, unsigned short* Al,
                          unsigned short* Bh, unsigned short* Bl,
                          unsigned short* Ch, unsigned short* Cl,
                          unsigned short* Dh, unsigned short* Dl) {
  int idx = blockIdx.x * 256 + threadIdx.x;
  unsigned short h, l;
  if (idx < 16384)      { split_f32(A[idx], h, l); Ah[idx] = h; Al[idx] = l; }
  else if (idx < 20480) { int i = idx - 16384; split_f32(B[i], h, l); Bh[i] = h; Bl[i] = l; }
  else if (idx < 24576) { int i = idx - 20480; split_f32(C[i], h, l); Ch[i] = h; Cl[i] = l; }
  else if (idx < 25600) { int i = idx - 24576; split_f32(D[i], h, l); Dh[i] = h; Dl[i] = l; }
}

// ---------------- 128x128 fp32 matmul (for A^2 ... A^64 squarings) ----------------
__global__ void k_mm128(const float* __restrict__ X, const float* __restrict__ Y,
                        float* __restrict__ Z, unsigned short* Zh, unsigned short* Zl,
                        int writeBF) {
  int gid = blockIdx.x * 256 + threadIdx.x;   // grid 64 -> 16384 outputs
  int row = gid >> 7, col = gid & 127;
  const float* xr = X + row * 128;
  float acc = 0.f;
  #pragma unroll 8
  for (int k = 0; k < 128; ++k) acc = fmaf(xr[k], Y[k * 128 + col], acc);
  if (writeBF) { unsigned short h, l; split_f32(acc, h, l); Zh[gid] = h; Zl[gid] = l; }
  else         { Z[gid] = acc; }
}

// ---------------- pass 1: local chunk scans (x0=0) -> v_c ----------------
__global__ __launch_bounds__(256, 1) void k_pass1(
    const float* __restrict__ d,
    const unsigned short* __restrict__ Ah, const unsigned short* __restrict__ Al,
    const unsigned short* __restrict__ Bh, const unsigned short* __restrict__ Bl,
    float* __restrict__ vout) {
  __shared__ unsigned short Xh[16][136];   // state hi plane (padded stride)
  __shared__ unsigned short Xl[16][136];   // state lo plane
  const int tid = threadIdx.x;
  const int w = tid >> 6, l = tid & 63, q = l >> 4, m = l & 15;
  const int g = blockIdx.x;

  // constant fragments in registers (B-operand: row n, 8 contiguous k)
  s8v fAh[2][4], fAl[2][4], fBh[2], fBl[2];
  #pragma unroll
  for (int t2 = 0; t2 < 2; ++t2) {
    const int n = (2 * w + t2) * 16 + m;
    #pragma unroll
    for (int kt = 0; kt < 4; ++kt) {
      const int k0 = kt * 32 + q * 8;
      fAh[t2][kt] = *(const s8v*)(Ah + n * 128 + k0);
      fAl[t2][kt] = *(const s8v*)(Al + n * 128 + k0);
    }
    fBh[t2] = *(const s8v*)(Bh + n * 32 + q * 8);
    fBl[t2] = *(const s8v*)(Bl + n * 32 + q * 8);
  }
  for (int i = tid; i < 16 * 136; i += 256) {
    ((unsigned short*)Xh)[i] = 0;
    ((unsigned short*)Xl)[i] = 0;
  }
  __syncthreads();

  const int ch = g * 16 + m, b = ch >> 6, chunk = ch & 63;
  const float* ubase = d + ((size_t)b * NN + chunk * 64) * NU + q * 8;

  #pragma unroll 1
  for (int j = 0; j < 64; ++j) {
    // u fragment (A-operand: m=chain, k=u index)
    const float* up = ubase + (size_t)j * NU;
    f32x4 u0 = *(const f32x4*)up;
    f32x4 u1 = *(const f32x4*)(up + 4);
    BF8 uh, ul;
    #pragma unroll
    for (int i = 0; i < 4; ++i) { split_f32(u0[i], uh.u[i], ul.u[i]); split_f32(u1[i], uh.u[4 + i], ul.u[4 + i]); }
    // X fragments (A-operand: m=chain row of LDS, 8 contiguous k)
    s8v fXh[4], fXl[4];
    #pragma unroll
    for (int kt = 0; kt < 4; ++kt) {
      fXh[kt] = *(const s8v*)&Xh[m][kt * 32 + q * 8];
      fXl[kt] = *(const s8v*)&Xl[m][kt * 32 + q * 8];
    }
    f32x4 acc[2];
    #pragma unroll
    for (int t2 = 0; t2 < 2; ++t2) {
      f32x4 a = {0.f, 0.f, 0.f, 0.f};
      #pragma unroll
      for (int kt = 0; kt < 4; ++kt) {
        a = mfma16(fXh[kt], fAh[t2][kt], a);
        a = mfma16(fXl[kt], fAh[t2][kt], a);
        a = mfma16(fXh[kt], fAl[t2][kt], a);
      }
      a = mfma16(uh.v, fBh[t2], a);
      a = mfma16(ul.v, fBh[t2], a);
      a = mfma16(uh.v, fBl[t2], a);
      acc[t2] = a;
    }
    __syncthreads();
    // write new X (C/D layout: row = q*4+r chain, col = n)
    #pragma unroll
    for (int t2 = 0; t2 < 2; ++t2) {
      const int col = (2 * w + t2) * 16 + m;
      #pragma unroll
      for (int r = 0; r < 4; ++r) {
        unsigned short h, lo;
        split_f32(acc[t2][r], h, lo);
        Xh[q * 4 + r][col] = h;
        Xl[q * 4 + r][col] = lo;
      }
    }
    __syncthreads();
  }
  // write v_c = final local state (fp32)
  const int lb = tid >> 4, i0 = (tid & 15) * 8;
  BF8 hh, ll;
  hh.v = *(const s8v*)&Xh[lb][i0];
  ll.v = *(const s8v*)&Xl[lb][i0];
  f32x4 o0, o1;
  #pragma unroll
  for (int i = 0; i < 4; ++i) { o0[i] = bf16_f(hh.u[i]) + bf16_f(ll.u[i]); o1[i] = bf16_f(hh.u[4 + i]) + bf16_f(ll.u[4 + i]); }
  float* vp = vout + ((size_t)(g * 16 + lb)) * 128 + i0;
  *(f32x4*)vp = o0;
  *(f32x4*)(vp + 4) = o1;
}

// ---------------- carry scan: s_{c+1} = A^64 s_c + v_c ----------------
__global__ __launch_bounds__(256, 1) void k_carry(
    const unsigned short* __restrict__ Gh, const unsigned short* __restrict__ Gl,
    const float* __restrict__ v, float* __restrict__ sout) {
  __shared__ unsigned short Xh[16][136];
  __shared__ unsigned short Xl[16][136];
  const int tid = threadIdx.x;
  const int w = tid >> 6, l = tid & 63, q = l >> 4, m = l & 15;
  const int g = blockIdx.x;    // 0..3, batches g*16 .. g*16+15

  s8v fGh[2][4], fGl[2][4];
  #pragma unroll
  for (int t2 = 0; t2 < 2; ++t2) {
    const int n = (2 * w + t2) * 16 + m;
    #pragma unroll
    for (int kt = 0; kt < 4; ++kt) {
      const int k0 = kt * 32 + q * 8;
      fGh[t2][kt] = *(const s8v*)(Gh + n * 128 + k0);
      fGl[t2][kt] = *(const s8v*)(Gl + n * 128 + k0);
    }
  }
  for (int i = tid; i < 16 * 136; i += 256) {
    ((unsigned short*)Xh)[i] = 0;
    ((unsigned short*)Xl)[i] = 0;
  }
  __syncthreads();

  const int lb = tid >> 4, i0 = (tid & 15) * 8;
  float* sbase = sout + ((size_t)(g * 16 + lb) * 64) * 128 + i0;

  #pragma unroll 1
  for (int c = 0; c < 64; ++c) {
    // store s_c (pre-update state)
    {
      BF8 hh, ll;
      hh.v = *(const s8v*)&Xh[lb][i0];
      ll.v = *(const s8v*)&Xl[lb][i0];
      f32x4 o0, o1;
      #pragma unroll
      for (int i = 0; i < 4; ++i) { o0[i] = bf16_f(hh.u[i]) + bf16_f(ll.u[i]); o1[i] = bf16_f(hh.u[4 + i]) + bf16_f(ll.u[4 + i]); }
      *(f32x4*)(sbase + (size_t)c * 128) = o0;
      *(f32x4*)(sbase + (size_t)c * 128 + 4) = o1;
    }
    s8v fXh[4], fXl[4];
    #pragma unroll
    for (int kt = 0; kt < 4; ++kt) {
      fXh[kt] = *(const s8v*)&Xh[m][kt * 32 + q * 8];
      fXl[kt] = *(const s8v*)&Xl[m][kt * 32 + q * 8];
    }
    f32x4 acc[2];
    #pragma unroll
    for (int t2 = 0; t2 < 2; ++t2) {
      const int nn = (2 * w + t2) * 16 + m;
      f32x4 a;
      #pragma unroll
      for (int r = 0; r < 4; ++r)   // acc init = v_c in C/D layout
        a[r] = v[((size_t)((g * 16 + q * 4 + r) * 64 + c)) * 128 + nn];
      #pragma unroll
      for (int kt = 0; kt < 4; ++kt) {
        a = mfma16(fXh[kt], fGh[t2][kt], a);
        a = mfma16(fXl[kt], fGh[t2][kt], a);
        a = mfma16(fXh[kt], fGl[t2][kt], a);
      }
      acc[t2] = a;
    }
    __syncthreads();
    #pragma unroll
    for (int t2 = 0; t2 < 2; ++t2) {
      const int col = (2 * w + t2) * 16 + m;
      #pragma unroll
      for (int r = 0; r < 4; ++r) {
        unsigned short h, lo;
        split_f32(acc[t2][r], h, lo);
        Xh[q * 4 + r][col] = h;
        Xl[q * 4 + r][col] = lo;
      }
    }
    __syncthreads();
  }
}

// ---------------- pass 2: re-scan chunks from s_c, write x and y ----------------
__global__ __launch_bounds__(256, 1) void k_pass2(
    const float* __restrict__ d, const float* __restrict__ s,
    const unsigned short* __restrict__ Ah, const unsigned short* __restrict__ Al,
    const unsigned short* __restrict__ Bh, const unsigned short* __restrict__ Bl,
    const unsigned short* __restrict__ Ch, const unsigned short* __restrict__ Cl,
    const unsigned short* __restrict__ Dh, const unsigned short* __restrict__ Dl,
    float* __restrict__ yout, float* __restrict__ xout) {
  __shared__ unsigned short Xh[16][136];
  __shared__ unsigned short Xl[16][136];
  const int tid = threadIdx.x;
  const int w = tid >> 6, l = tid & 63, q = l >> 4, m = l & 15;
  const int g = blockIdx.x;

  s8v fAh[2][4], fAl[2][4], fBh[2], fBl[2];
  #pragma unroll
  for (int t2 = 0; t2 < 2; ++t2) {
    const int n = (2 * w + t2) * 16 + m;
    #pragma unroll
    for (int kt = 0; kt < 4; ++kt) {
      const int k0 = kt * 32 + q * 8;
      fAh[t2][kt] = *(const s8v*)(Ah + n * 128 + k0);
      fAl[t2][kt] = *(const s8v*)(Al + n * 128 + k0);
    }
    fBh[t2] = *(const s8v*)(Bh + n * 32 + q * 8);
    fBl[t2] = *(const s8v*)(Bl + n * 32 + q * 8);
  }
  // C/D fragments (used by waves 0,1 which own the two 16-col y tiles)
  s8v fCh[4], fCl[4], fDh, fDl;
  {
    const int o = (w & 1) * 16 + m;
    #pragma unroll
    for (int kt = 0; kt < 4; ++kt) {
      const int k0 = kt * 32 + q * 8;
      fCh[kt] = *(const s8v*)(Ch + o * 128 + k0);
      fCl[kt] = *(const s8v*)(Cl + o * 128 + k0);
    }
    fDh = *(const s8v*)(Dh + o * 32 + q * 8);
    fDl = *(const s8v*)(Dl + o * 32 + q * 8);
  }

  const int lb = tid >> 4, i0 = (tid & 15) * 8;
  // init X from carry state s (flat chain index = b*64 + chunk)
  {
    const float* sp = s + ((size_t)(g * 16 + lb)) * 128 + i0;
    BF8 hh, ll;
    #pragma unroll
    for (int i = 0; i < 8; ++i) split_f32(sp[i], hh.u[i], ll.u[i]);
    *(s8v*)&Xh[lb][i0] = hh.v;
    *(s8v*)&Xl[lb][i0] = ll.v;
  }
  __syncthreads();

  const int ch = g * 16 + m, b = ch >> 6, chunk = ch & 63;
  const float* ubase = d + ((size_t)b * NN + chunk * 64) * NU + q * 8;

  const int chS = g * 16 + lb, bS = chS >> 6, chunkS = chS & 63;
  float* xbase = xout + ((size_t)bS * (NN + 1) + (size_t)chunkS * 64) * NX + i0;

  #pragma unroll 1
  for (int j = 0; j < 64; ++j) {
    const float* up = ubase + (size_t)j * NU;
    f32x4 u0 = *(const f32x4*)up;
    f32x4 u1 = *(const f32x4*)(up + 4);
    BF8 uh, ul;
    #pragma unroll
    for (int i = 0; i < 4; ++i) { split_f32(u0[i], uh.u[i], ul.u[i]); split_f32(u1[i], uh.u[4 + i], ul.u[4 + i]); }

    s8v fXh[4], fXl[4];
    #pragma unroll
    for (int kt = 0; kt < 4; ++kt) {
      fXh[kt] = *(const s8v*)&Xh[m][kt * 32 + q * 8];
      fXl[kt] = *(const s8v*)&Xl[m][kt * 32 + q * 8];
    }

    // x output (pre-update state), coalesced 512B per chain
    {
      BF8 hh, ll;
      hh.v = *(const s8v*)&Xh[lb][i0];
      ll.v = *(const s8v*)&Xl[lb][i0];
      f32x4 o0, o1;
      #pragma unroll
      for (int i = 0; i < 4; ++i) { o0[i] = bf16_f(hh.u[i]) + bf16_f(ll.u[i]); o1[i] = bf16_f(hh.u[4 + i]) + bf16_f(ll.u[4 + i]); }
      *(f32x4*)(xbase + (size_t)j * NX) = o0;
      *(f32x4*)(xbase + (size_t)j * NX + 4) = o1;
    }

    // X update: X <- X A^T + u B^T   (3-term bf16 hi/lo split)
    f32x4 acc[2];
    #pragma unroll
    for (int t2 = 0; t2 < 2; ++t2) {
      f32x4 a = {0.f, 0.f, 0.f, 0.f};
      #pragma unroll
      for (int kt = 0; kt < 4; ++kt) {
        a = mfma16(fXh[kt], fAh[t2][kt], a);
        a = mfma16(fXl[kt], fAh[t2][kt], a);
        a = mfma16(fXh[kt], fAl[t2][kt], a);
      }
      a = mfma16(uh.v, fBh[t2], a);
      a = mfma16(ul.v, fBh[t2], a);
      a = mfma16(uh.v, fBl[t2], a);
      acc[t2] = a;
    }

    // y = C x_pre + D u  (waves 0,1)
    if (w < 2) {
      f32x4 ay = {0.f, 0.f, 0.f, 0.f};
      #pragma unroll
      for (int kt = 0; kt < 4; ++kt) {
        ay = mfma16(fXh[kt], fCh[kt], ay);
        ay = mfma16(fXl[kt], fCh[kt], ay);
        ay = mfma16(fXh[kt], fCl[kt], ay);
      }
      ay = mfma16(uh.v, fDh, ay);
      ay = mfma16(ul.v, fDh, ay);
      ay = mfma16(uh.v, fDl, ay);
      #pragma unroll
      for (int r = 0; r < 4; ++r) {
        const int chY = g * 16 + q * 4 + r;
        const int bY = chY >> 6;
        const int kY = (chY & 63) * 64 + j;
        yout[((size_t)bY * NN + kY) * NY + w * 16 + m] = ay[r];
      }
    }
    __syncthreads();
    #pragma unroll
    for (int t2 = 0; t2 < 2; ++t2) {
      const int col = (2 * w + t2) * 16 + m;
      #pragma unroll
      for (int r = 0; r < 4; ++r) {
        unsigned short h, lo;
        split_f32(acc[t2][r], h, lo);
        Xh[q * 4 + r][col] = h;
        Xl[q * 4 + r][col] = lo;
      }
    }
    __syncthreads();
  }
  // x_N: final state of chunk 63 of each batch
  if ((g & 3) == 3 && lb == 15) {
    BF8 hh, ll;
    hh.v = *(const s8v*)&Xh[15][i0];
    ll.v = *(const s8v*)&Xl[15][i0];
    f32x4 o0, o1;
    #pragma unroll
    for (int i = 0; i < 4; ++i) { o0[i] = bf16_f(hh.u[i]) + bf16_f(ll.u[i]); o1[i] = bf16_f(hh.u[4 + i]) + bf16_f(ll.u[4 + i]); }
    float* fp = xout + ((size_t)(g >> 2) * (NN + 1) + NN) * NX + i0;
    *(f32x4*)fp = o0;
    *(f32x4*)(fp + 4) = o1;
  }
}

// ---------------- launcher ----------------
extern "C" void kernel_launch(void* const* d_in, const int* in_sizes, int n_in,
                              void* d_out, int out_size, void* d_ws, size_t ws_size,
                              hipStream_t stream) {
  (void)in_sizes; (void)n_in; (void)out_size; (void)ws_size;
  const float* d = (const float*)d_in[0];
  const float* A = (const float*)d_in[1];
  const float* B = (const float*)d_in[2];
  const float* C = (const float*)d_in[3];
  const float* D = (const float*)d_in[4];

  char* ws = (char*)d_ws;
  unsigned short* Ah = (unsigned short*)(ws + OFF_AH);
  unsigned short* Al = (unsigned short*)(ws + OFF_AL);
  unsigned short* Bh = (unsigned short*)(ws + OFF_BH);
  unsigned short* Bl = (unsigned short*)(ws + OFF_BL);
  unsigned short* Chp = (unsigned short*)(ws + OFF_CH);
  unsigned short* Clp = (unsigned short*)(ws + OFF_CL);
  unsigned short* Dhp = (unsigned short*)(ws + OFF_DH);
  unsigned short* Dlp = (unsigned short*)(ws + OFF_DL);
  unsigned short* Gh = (unsigned short*)(ws + OFF_GH);
  unsigned short* Gl = (unsigned short*)(ws + OFF_GL);
  float* P0 = (float*)(ws + OFF_P0);
  float* P1 = (float*)(ws + OFF_P1);
  float* V  = (float*)(ws + OFF_V);
  float* S  = (float*)(ws + OFF_S);

  float* yout = (float*)d_out;
  float* xout = yout + (size_t)BATCH * NN * NY;   // x follows y in flat output

  k_convert<<<100, 256, 0, stream>>>(A, B, C, D, Ah, Al, Bh, Bl, Chp, Clp, Dhp, Dlp);
  // A^64 by repeated squaring (fp32)
  k_mm128<<<64, 256, 0, stream>>>(A,  A,  P0, nullptr, nullptr, 0);  // A^2
  k_mm128<<<64, 256, 0, stream>>>(P0, P0, P1, nullptr, nullptr, 0);  // A^4
  k_mm128<<<64, 256, 0, stream>>>(P1, P1, P0, nullptr, nullptr, 0);  // A^8
  k_mm128<<<64, 256, 0, stream>>>(P0, P0, P1, nullptr, nullptr, 0);  // A^16
  k_mm128<<<64, 256, 0, stream>>>(P1, P1, P0, nullptr, nullptr, 0);  // A^32
  k_mm128<<<64, 256, 0, stream>>>(P0, P0, nullptr, Gh, Gl, 1);       // A^64 -> bf16 hi/lo

  k_pass1<<<256, 256, 0, stream>>>(d, Ah, Al, Bh, Bl, V);
  k_carry<<<4, 256, 0, stream>>>(Gh, Gl, V, S);
  k_pass2<<<256, 256, 0, stream>>>(d, S, Ah, Al, Bh, Bl, Chp, Clp, Dhp, Dlp, yout, xout);
}

// Round 2
// 342.131 us; speedup vs baseline: 1.2358x; 1.2358x over previous
//
#include <hip/hip_runtime.h>
#include <stdint.h>
#include <stddef.h>

// ---------------- types & helpers ----------------
typedef short s8v   __attribute__((ext_vector_type(8)));  // 8 bf16 in shorts (4 VGPRs)
typedef float f32x4 __attribute__((ext_vector_type(4)));

union BF8 { s8v v; unsigned short u[8]; };

__device__ __forceinline__ unsigned short bf16_rn(float x) {
  unsigned u = __builtin_bit_cast(unsigned, x);
  u += 0x7FFFu + ((u >> 16) & 1u);            // round-to-nearest-even
  return (unsigned short)(u >> 16);
}
__device__ __forceinline__ float bf16_f(unsigned short h) {
  unsigned u = ((unsigned)h) << 16;
  return __builtin_bit_cast(float, u);
}
__device__ __forceinline__ void split_f32(float x, unsigned short &h, unsigned short &l) {
  unsigned short hs = bf16_rn(x);
  h = hs;
  l = bf16_rn(x - bf16_f(hs));
}
__device__ __forceinline__ f32x4 mfma16(s8v a, s8v b, f32x4 c) {
  return __builtin_amdgcn_mfma_f32_16x16x32_bf16(a, b, c, 0, 0, 0);
}
__device__ __forceinline__ s8v cvt8(const float* p) {   // 8 fp32 -> 8 bf16 (hi only)
  BF8 r;
  f32x4 x0 = *(const f32x4*)p, x1 = *(const f32x4*)(p + 4);
  #pragma unroll
  for (int i = 0; i < 4; ++i) { r.u[i] = bf16_rn(x0[i]); r.u[4 + i] = bf16_rn(x1[i]); }
  return r.v;
}

// ---------------- problem sizes ----------------
#define BATCH 64
#define NN    4096
#define NX    128
#define NU    32
#define NY    32
// chunking: L=64 steps per chunk, 64 chunks per batch -> 4096 chains

// ---------------- workspace byte offsets ----------------
#define OFF_AH 0
#define OFF_AL 32768
#define OFF_BH 65536
#define OFF_BL 73728
#define OFF_CH 81920
#define OFF_CL 90112
#define OFF_DH 98304
#define OFF_DL 100352
#define OFF_GH 102400      // A^64 hi
#define OFF_GL 135168      // A^64 lo
#define OFF_P0 167936      // fp32 128x128 ping
#define OFF_P1 233472      // fp32 128x128 pong
#define OFF_V  299008      // v: 4096 x 128 fp32 (2 MB)
#define OFF_S  2396160     // s: 4096 x 128 fp32 (2 MB)
#define OFF_G2H 4493312    // A^128 hi
#define OFF_G2L 4526080
#define OFF_G3H 4558848    // A^192 hi
#define OFF_G3L 4591616
#define OFF_P2  4624384    // fp32 128x128 extra
// total ~4.7 MB of d_ws

// ---------------- prep: split A,B,C,D into bf16 hi/lo ----------------
__global__ void k_convert(const float* __restrict__ A, const float* __restrict__ B,
                          const float* __restrict__ C, const float* __restrict__ D,
                          unsigned short* Ah, unsigned short* Al,
                          unsigned short* Bh, unsigned short* Bl,
                          unsigned short* Ch, unsigned short* Cl,
                          unsigned short* Dh, unsigned short* Dl) {
  int idx = blockIdx.x * 256 + threadIdx.x;
  unsigned short h, l;
  if (idx < 16384)      { split_f32(A[idx], h, l); Ah[idx] = h; Al[idx] = l; }
  else if (idx < 20480) { int i = idx - 16384; split_f32(B[i], h, l); Bh[i] = h; Bl[i] = l; }
  else if (idx < 24576) { int i = idx - 20480; split_f32(C[i], h, l); Ch[i] = h; Cl[i] = l; }
  else if (idx < 25600) { int i = idx - 24576; split_f32(D[i], h, l); Dh[i] = h; Dl[i] = l; }
}

// ---------------- 128x128 fp32 matmul (powers of A) ----------------
__global__ void k_mm128(const float* __restrict__ X, const float* __restrict__ Y,
                        float* __restrict__ Z, unsigned short* Zh, unsigned short* Zl,
                        int writeBF) {
  int gid = blockIdx.x * 256 + threadIdx.x;   // grid 64 -> 16384 outputs
  int row = gid >> 7, col = gid & 127;
  const float* xr = X + row * 128;
  float acc = 0.f;
  #pragma unroll 8
  for (int k = 0; k < 128; ++k) acc = fmaf(xr[k], Y[k * 128 + col], acc);
  Z[gid] = acc;
  if (writeBF) { unsigned short h, l; split_f32(acc, h, l); Zh[gid] = h; Zl[gid] = l; }
}

// ---------------- pass 1: local chunk scans (x0=0) -> v_c ----------------
__global__ __launch_bounds__(256) void k_pass1(
    const float* __restrict__ d,
    const unsigned short* __restrict__ Ah, const unsigned short* __restrict__ Al,
    const unsigned short* __restrict__ Bh, const unsigned short* __restrict__ Bl,
    float* __restrict__ vout) {
  __shared__ unsigned short Xh[2][16][136];   // ping-pong state hi plane
  __shared__ unsigned short Xl[2][16][136];   // ping-pong state lo plane
  const int tid = threadIdx.x;
  const int w = tid >> 6, l = tid & 63, q = l >> 4, m = l & 15;
  const int g = blockIdx.x;

  // constant fragments in registers (B-operand: row n, 8 contiguous k)
  s8v fAh[2][4], fAl[2][4], fBh[2], fBl[2];
  #pragma unroll
  for (int t2 = 0; t2 < 2; ++t2) {
    const int n = (2 * w + t2) * 16 + m;
    #pragma unroll
    for (int kt = 0; kt < 4; ++kt) {
      const int k0 = kt * 32 + q * 8;
      fAh[t2][kt] = *(const s8v*)(Ah + n * 128 + k0);
      fAl[t2][kt] = *(const s8v*)(Al + n * 128 + k0);
    }
    fBh[t2] = *(const s8v*)(Bh + n * 32 + q * 8);
    fBl[t2] = *(const s8v*)(Bl + n * 32 + q * 8);
  }
  for (int i = tid; i < 16 * 136; i += 256) {
    ((unsigned short*)Xh[0])[i] = 0;
    ((unsigned short*)Xl[0])[i] = 0;
  }
  __syncthreads();

  const int ch = g * 16 + m, b = ch >> 6, chunk = ch & 63;
  const float* ubase = d + ((size_t)b * NN + chunk * 64) * NU + q * 8;

  f32x4 cu0 = *(const f32x4*)ubase;
  f32x4 cu1 = *(const f32x4*)(ubase + 4);

  #pragma unroll 2
  for (int j = 0; j < 64; ++j) {
    const int p = j & 1;
    // prefetch next u (issues before the compute body; hidden by it)
    f32x4 nu0 = cu0, nu1 = cu1;
    if (j < 63) {
      const float* up = ubase + (size_t)(j + 1) * NU;
      nu0 = *(const f32x4*)up;
      nu1 = *(const f32x4*)(up + 4);
    }
    BF8 uh, ul;
    #pragma unroll
    for (int i = 0; i < 4; ++i) { split_f32(cu0[i], uh.u[i], ul.u[i]); split_f32(cu1[i], uh.u[4 + i], ul.u[4 + i]); }
    s8v fXh[4], fXl[4];
    #pragma unroll
    for (int kt = 0; kt < 4; ++kt) {
      fXh[kt] = *(const s8v*)&Xh[p][m][kt * 32 + q * 8];
      fXl[kt] = *(const s8v*)&Xl[p][m][kt * 32 + q * 8];
    }
    f32x4 acc[2];
    #pragma unroll
    for (int t2 = 0; t2 < 2; ++t2) {
      f32x4 a0 = {0.f,0.f,0.f,0.f}, a1 = {0.f,0.f,0.f,0.f}, a2 = {0.f,0.f,0.f,0.f};
      #pragma unroll
      for (int kt = 0; kt < 4; ++kt) a0 = mfma16(fXh[kt], fAh[t2][kt], a0);
      a0 = mfma16(uh.v, fBh[t2], a0);
      #pragma unroll
      for (int kt = 0; kt < 4; ++kt) a1 = mfma16(fXl[kt], fAh[t2][kt], a1);
      a1 = mfma16(ul.v, fBh[t2], a1);
      #pragma unroll
      for (int kt = 0; kt < 4; ++kt) a2 = mfma16(fXh[kt], fAl[t2][kt], a2);
      a2 = mfma16(uh.v, fBl[t2], a2);
      acc[t2] = a0 + a1 + a2;
    }
    // write new X to the other buffer (C/D layout: row = q*4+r, col = n)
    #pragma unroll
    for (int t2 = 0; t2 < 2; ++t2) {
      const int col = (2 * w + t2) * 16 + m;
      #pragma unroll
      for (int r = 0; r < 4; ++r) {
        unsigned short h, lo;
        split_f32(acc[t2][r], h, lo);
        Xh[1 - p][q * 4 + r][col] = h;
        Xl[1 - p][q * 4 + r][col] = lo;
      }
    }
    __syncthreads();
    cu0 = nu0; cu1 = nu1;
  }
  // final state is in buffer 0 (64 iterations)
  const int lb = tid >> 4, i0 = (tid & 15) * 8;
  BF8 hh, ll;
  hh.v = *(const s8v*)&Xh[0][lb][i0];
  ll.v = *(const s8v*)&Xl[0][lb][i0];
  f32x4 o0, o1;
  #pragma unroll
  for (int i = 0; i < 4; ++i) { o0[i] = bf16_f(hh.u[i]) + bf16_f(ll.u[i]); o1[i] = bf16_f(hh.u[4 + i]) + bf16_f(ll.u[4 + i]); }
  float* vp = vout + ((size_t)(g * 16 + lb)) * 128 + i0;
  *(f32x4*)vp = o0;
  *(f32x4*)(vp + 4) = o1;
}

// ---------------- parallel windowed carry: s_c = v_{c-1} + G v_{c-2} + G2 v_{c-3} + G3 v_{c-4} ----------------
// G^4 = A^256 term is negligible (rho(A)=0.9 -> |A^256| <~ 1e-9).
__global__ __launch_bounds__(256) void k_carry2(
    const unsigned short* __restrict__ Gh, const unsigned short* __restrict__ G2h,
    const unsigned short* __restrict__ G3h,
    const float* __restrict__ v, float* __restrict__ sout) {
  const int tid = threadIdx.x;
  const int w = tid >> 6, l = tid & 63, q = l >> 4, m = l & 15;
  const int g = blockIdx.x;

  // B-operand fragments for G, G2, G3 (single bf16: terms are ~1e-3 scale)
  s8v f1[2][4], f2[2][4], f3[2][4];
  #pragma unroll
  for (int t2 = 0; t2 < 2; ++t2) {
    const int n = (2 * w + t2) * 16 + m;
    #pragma unroll
    for (int kt = 0; kt < 4; ++kt) {
      const int k0 = kt * 32 + q * 8;
      f1[t2][kt] = *(const s8v*)(Gh  + n * 128 + k0);
      f2[t2][kt] = *(const s8v*)(G2h + n * 128 + k0);
      f3[t2][kt] = *(const s8v*)(G3h + n * 128 + k0);
    }
  }
  const int ch = g * 16 + m, c = ch & 63;
  const s8v zero = {0,0,0,0,0,0,0,0};
  s8v a2f[4], a3f[4], a4f[4];
  #pragma unroll
  for (int kt = 0; kt < 4; ++kt) {
    const int k0 = kt * 32 + q * 8;
    a2f[kt] = (c >= 2) ? cvt8(v + (size_t)(ch - 2) * 128 + k0) : zero;
    a3f[kt] = (c >= 3) ? cvt8(v + (size_t)(ch - 3) * 128 + k0) : zero;
    a4f[kt] = (c >= 4) ? cvt8(v + (size_t)(ch - 4) * 128 + k0) : zero;
  }
  f32x4 acc[2];
  #pragma unroll
  for (int t2 = 0; t2 < 2; ++t2) {
    f32x4 a = {0.f,0.f,0.f,0.f};
    #pragma unroll
    for (int kt = 0; kt < 4; ++kt) {
      a = mfma16(a2f[kt], f1[t2][kt], a);
      a = mfma16(a3f[kt], f2[t2][kt], a);
      a = mfma16(a4f[kt], f3[t2][kt], a);
    }
    acc[t2] = a;
  }
  // epilogue: add v_{c-1} exactly in fp32 (dominant term), store s
  #pragma unroll
  for (int t2 = 0; t2 < 2; ++t2) {
    #pragma unroll
    for (int r = 0; r < 4; ++r) {
      const int row = q * 4 + r, chr = g * 16 + row, cr = chr & 63;
      const int col = (2 * w + t2) * 16 + m;
      float sval = 0.f;
      if (cr >= 1) sval = acc[t2][r] + v[(size_t)(chr - 1) * 128 + col];
      sout[(size_t)chr * 128 + col] = sval;
    }
  }
}

// ---------------- pass 2: re-scan chunks from s_c, write x and y ----------------
__global__ __launch_bounds__(256) void k_pass2(
    const float* __restrict__ d, const float* __restrict__ s,
    const unsigned short* __restrict__ Ah, const unsigned short* __restrict__ Al,
    const unsigned short* __restrict__ Bh, const unsigned short* __restrict__ Bl,
    const unsigned short* __restrict__ Ch, const unsigned short* __restrict__ Cl,
    const unsigned short* __restrict__ Dh, const unsigned short* __restrict__ Dl,
    float* __restrict__ yout, float* __restrict__ xout) {
  __shared__ unsigned short Xh[2][16][136];
  __shared__ unsigned short Xl[2][16][136];
  const int tid = threadIdx.x;
  const int w = tid >> 6, l = tid & 63, q = l >> 4, m = l & 15;
  const int g = blockIdx.x;

  s8v fAh[2][4], fAl[2][4], fBh[2], fBl[2];
  #pragma unroll
  for (int t2 = 0; t2 < 2; ++t2) {
    const int n = (2 * w + t2) * 16 + m;
    #pragma unroll
    for (int kt = 0; kt < 4; ++kt) {
      const int k0 = kt * 32 + q * 8;
      fAh[t2][kt] = *(const s8v*)(Ah + n * 128 + k0);
      fAl[t2][kt] = *(const s8v*)(Al + n * 128 + k0);
    }
    fBh[t2] = *(const s8v*)(Bh + n * 32 + q * 8);
    fBl[t2] = *(const s8v*)(Bl + n * 32 + q * 8);
  }
  // C/D fragments (used by waves 0,1 which own the two 16-col y tiles)
  s8v fCh[4], fCl[4], fDh, fDl;
  {
    const int o = (w & 1) * 16 + m;
    #pragma unroll
    for (int kt = 0; kt < 4; ++kt) {
      const int k0 = kt * 32 + q * 8;
      fCh[kt] = *(const s8v*)(Ch + o * 128 + k0);
      fCl[kt] = *(const s8v*)(Cl + o * 128 + k0);
    }
    fDh = *(const s8v*)(Dh + o * 32 + q * 8);
    fDl = *(const s8v*)(Dl + o * 32 + q * 8);
  }

  const int lb = tid >> 4, i0 = (tid & 15) * 8;
  // init X (buffer 0) from carry state s
  {
    const float* sp = s + ((size_t)(g * 16 + lb)) * 128 + i0;
    BF8 hh, ll;
    #pragma unroll
    for (int i = 0; i < 8; ++i) split_f32(sp[i], hh.u[i], ll.u[i]);
    *(s8v*)&Xh[0][lb][i0] = hh.v;
    *(s8v*)&Xl[0][lb][i0] = ll.v;
  }
  __syncthreads();

  const int ch = g * 16 + m, b = ch >> 6, chunk = ch & 63;
  const float* ubase = d + ((size_t)b * NN + chunk * 64) * NU + q * 8;

  const int chS = g * 16 + lb, bS = chS >> 6, chunkS = chS & 63;
  float* xbase = xout + ((size_t)bS * (NN + 1) + (size_t)chunkS * 64) * NX + i0;

  f32x4 cu0 = *(const f32x4*)ubase;
  f32x4 cu1 = *(const f32x4*)(ubase + 4);

  #pragma unroll 2
  for (int j = 0; j < 64; ++j) {
    const int p = j & 1;
    f32x4 nu0 = cu0, nu1 = cu1;
    if (j < 63) {
      const float* up = ubase + (size_t)(j + 1) * NU;
      nu0 = *(const f32x4*)up;
      nu1 = *(const f32x4*)(up + 4);
    }
    BF8 uh, ul;
    #pragma unroll
    for (int i = 0; i < 4; ++i) { split_f32(cu0[i], uh.u[i], ul.u[i]); split_f32(cu1[i], uh.u[4 + i], ul.u[4 + i]); }

    s8v fXh[4], fXl[4];
    #pragma unroll
    for (int kt = 0; kt < 4; ++kt) {
      fXh[kt] = *(const s8v*)&Xh[p][m][kt * 32 + q * 8];
      fXl[kt] = *(const s8v*)&Xl[p][m][kt * 32 + q * 8];
    }

    // x output (pre-update state), coalesced 512B per chain
    {
      BF8 hh, ll;
      hh.v = *(const s8v*)&Xh[p][lb][i0];
      ll.v = *(const s8v*)&Xl[p][lb][i0];
      f32x4 o0, o1;
      #pragma unroll
      for (int i = 0; i < 4; ++i) { o0[i] = bf16_f(hh.u[i]) + bf16_f(ll.u[i]); o1[i] = bf16_f(hh.u[4 + i]) + bf16_f(ll.u[4 + i]); }
      *(f32x4*)(xbase + (size_t)j * NX) = o0;
      *(f32x4*)(xbase + (size_t)j * NX + 4) = o1;
    }

    // X update: X <- X A^T + u B^T  (3 independent MFMA chains per tile)
    f32x4 acc[2];
    #pragma unroll
    for (int t2 = 0; t2 < 2; ++t2) {
      f32x4 a0 = {0.f,0.f,0.f,0.f}, a1 = {0.f,0.f,0.f,0.f}, a2 = {0.f,0.f,0.f,0.f};
      #pragma unroll
      for (int kt = 0; kt < 4; ++kt) a0 = mfma16(fXh[kt], fAh[t2][kt], a0);
      a0 = mfma16(uh.v, fBh[t2], a0);
      #pragma unroll
      for (int kt = 0; kt < 4; ++kt) a1 = mfma16(fXl[kt], fAh[t2][kt], a1);
      a1 = mfma16(ul.v, fBh[t2], a1);
      #pragma unroll
      for (int kt = 0; kt < 4; ++kt) a2 = mfma16(fXh[kt], fAl[t2][kt], a2);
      a2 = mfma16(uh.v, fBl[t2], a2);
      acc[t2] = a0 + a1 + a2;
    }

    // y = C x_pre + D u  (waves 0,1)
    if (w < 2) {
      f32x4 b0 = {0.f,0.f,0.f,0.f}, b1 = {0.f,0.f,0.f,0.f}, b2 = {0.f,0.f,0.f,0.f};
      #pragma unroll
      for (int kt = 0; kt < 4; ++kt) b0 = mfma16(fXh[kt], fCh[kt], b0);
      b0 = mfma16(uh.v, fDh, b0);
      #pragma unroll
      for (int kt = 0; kt < 4; ++kt) b1 = mfma16(fXl[kt], fCh[kt], b1);
      b1 = mfma16(ul.v, fDh, b1);
      #pragma unroll
      for (int kt = 0; kt < 4; ++kt) b2 = mfma16(fXh[kt], fCl[kt], b2);
      b2 = mfma16(uh.v, fDl, b2);
      f32x4 ay = b0 + b1 + b2;
      #pragma unroll
      for (int r = 0; r < 4; ++r) {
        const int chY = g * 16 + q * 4 + r;
        const int bY = chY >> 6;
        const int kY = (chY & 63) * 64 + j;
        yout[((size_t)bY * NN + kY) * NY + w * 16 + m] = ay[r];
      }
    }
    #pragma unroll
    for (int t2 = 0; t2 < 2; ++t2) {
      const int col = (2 * w + t2) * 16 + m;
      #pragma unroll
      for (int r = 0; r < 4; ++r) {
        unsigned short h, lo;
        split_f32(acc[t2][r], h, lo);
        Xh[1 - p][q * 4 + r][col] = h;
        Xl[1 - p][q * 4 + r][col] = lo;
      }
    }
    __syncthreads();
    cu0 = nu0; cu1 = nu1;
  }
  // x_N: final state (buffer 0) of chunk 63 of each batch
  if ((g & 3) == 3 && lb == 15) {
    BF8 hh, ll;
    hh.v = *(const s8v*)&Xh[0][15][i0];
    ll.v = *(const s8v*)&Xl[0][15][i0];
    f32x4 o0, o1;
    #pragma unroll
    for (int i = 0; i < 4; ++i) { o0[i] = bf16_f(hh.u[i]) + bf16_f(ll.u[i]); o1[i] = bf16_f(hh.u[4 + i]) + bf16_f(ll.u[4 + i]); }
    float* fp = xout + ((size_t)(g >> 2) * (NN + 1) + NN) * NX + i0;
    *(f32x4*)fp = o0;
    *(f32x4*)(fp + 4) = o1;
  }
}

// ---------------- launcher ----------------
extern "C" void kernel_launch(void* const* d_in, const int* in_sizes, int n_in,
                              void* d_out, int out_size, void* d_ws, size_t ws_size,
                              hipStream_t stream) {
  (void)in_sizes; (void)n_in; (void)out_size; (void)ws_size;
  const float* d = (const float*)d_in[0];
  const float* A = (const float*)d_in[1];
  const float* B = (const float*)d_in[2];
  const float* C = (const float*)d_in[3];
  const float* D = (const float*)d_in[4];

  char* ws = (char*)d_ws;
  unsigned short* Ah = (unsigned short*)(ws + OFF_AH);
  unsigned short* Al = (unsigned short*)(ws + OFF_AL);
  unsigned short* Bh = (unsigned short*)(ws + OFF_BH);
  unsigned short* Bl = (unsigned short*)(ws + OFF_BL);
  unsigned short* Chp = (unsigned short*)(ws + OFF_CH);
  unsigned short* Clp = (unsigned short*)(ws + OFF_CL);
  unsigned short* Dhp = (unsigned short*)(ws + OFF_DH);
  unsigned short* Dlp = (unsigned short*)(ws + OFF_DL);
  unsigned short* Gh  = (unsigned short*)(ws + OFF_GH);
  unsigned short* Gl  = (unsigned short*)(ws + OFF_GL);
  unsigned short* G2h = (unsigned short*)(ws + OFF_G2H);
  unsigned short* G2l = (unsigned short*)(ws + OFF_G2L);
  unsigned short* G3h = (unsigned short*)(ws + OFF_G3H);
  unsigned short* G3l = (unsigned short*)(ws + OFF_G3L);
  float* P0 = (float*)(ws + OFF_P0);
  float* P1 = (float*)(ws + OFF_P1);
  float* P2 = (float*)(ws + OFF_P2);
  float* V  = (float*)(ws + OFF_V);
  float* S  = (float*)(ws + OFF_S);

  float* yout = (float*)d_out;
  float* xout = yout + (size_t)BATCH * NN * NY;   // x follows y in flat output

  k_convert<<<100, 256, 0, stream>>>(A, B, C, D, Ah, Al, Bh, Bl, Chp, Clp, Dhp, Dlp);
  // powers of A by repeated squaring (fp32)
  k_mm128<<<64, 256, 0, stream>>>(A,  A,  P0, nullptr, nullptr, 0);  // A^2
  k_mm128<<<64, 256, 0, stream>>>(P0, P0, P1, nullptr, nullptr, 0);  // A^4
  k_mm128<<<64, 256, 0, stream>>>(P1, P1, P0, nullptr, nullptr, 0);  // A^8
  k_mm128<<<64, 256, 0, stream>>>(P0, P0, P1, nullptr, nullptr, 0);  // A^16
  k_mm128<<<64, 256, 0, stream>>>(P1, P1, P0, nullptr, nullptr, 0);  // A^32
  k_mm128<<<64, 256, 0, stream>>>(P0, P0, P1, Gh,  Gl,  1);          // A^64
  k_mm128<<<64, 256, 0, stream>>>(P1, P1, P2, G2h, G2l, 1);          // A^128
  k_mm128<<<64, 256, 0, stream>>>(P2, P1, P0, G3h, G3l, 1);          // A^192

  k_pass1<<<256, 256, 0, stream>>>(d, Ah, Al, Bh, Bl, V);
  k_carry2<<<256, 256, 0, stream>>>(Gh, G2h, G3h, V, S);
  k_pass2<<<256, 256, 0, stream>>>(d, S, Ah, Al, Bh, Bl, Chp, Clp, Dhp, Dlp, yout, xout);
}

// Round 3
// 300.102 us; speedup vs baseline: 1.4089x; 1.1400x over previous
//
#include <hip/hip_runtime.h>
#include <stdint.h>
#include <stddef.h>

typedef unsigned short ushort_t;
typedef short s8v   __attribute__((ext_vector_type(8)));  // 8 bf16 (4 VGPRs)
typedef float f32x4 __attribute__((ext_vector_type(4)));

union BF8 { s8v v; unsigned short u[8]; };

__device__ __forceinline__ float bf16_f(unsigned short h) {
  unsigned u = ((unsigned)h) << 16;
  return __builtin_bit_cast(float, u);
}
// truncation split: h = top16(x) (err <= 2^-8 rel), residual exact (Sterbenz), l = top16(resid)
__device__ __forceinline__ void split_trunc(float x, unsigned short &h, unsigned short &l) {
  unsigned u = __builtin_bit_cast(unsigned, x);
  h = (unsigned short)(u >> 16);
  float hi = __builtin_bit_cast(float, u & 0xFFFF0000u);
  float r = x - hi;
  l = (unsigned short)(__builtin_bit_cast(unsigned, r) >> 16);
}
__device__ __forceinline__ f32x4 mfma16(s8v a, s8v b, f32x4 c) {
  return __builtin_amdgcn_mfma_f32_16x16x32_bf16(a, b, c, 0, 0, 0);
}
// split 8 contiguous fp32 -> hi/lo bf16 fragments
__device__ __forceinline__ void split8(f32x4 a, f32x4 b, s8v &h, s8v &l) {
  BF8 hh, ll;
  #pragma unroll
  for (int i = 0; i < 4; ++i) { split_trunc(a[i], hh.u[i], ll.u[i]); split_trunc(b[i], hh.u[4 + i], ll.u[4 + i]); }
  h = hh.v; l = ll.v;
}

#define BATCH 64
#define NN    4096
#define NX    128
#define NU    32
#define NY    32
#define LPAD  132   // LDS row stride in shorts: 66 dwords == 2 mod 32 (4-way reads, 2-way writes)

// ---------------- workspace byte offsets ----------------
#define OFF_AH   0
#define OFF_AL   32768
#define OFF_BH   65536
#define OFF_BL   73728
#define OFF_CH   81920
#define OFF_CL   90112
#define OFF_DH   98304
#define OFF_DL   100352
#define OFF_GH   102400
#define OFF_GL   135168
#define OFF_P0   167936
#define OFF_P1   233472
#define OFF_V    299008
#define OFF_S    2396160
#define OFF_A2H  4493312
#define OFF_A2L  4526080
#define OFF_ABH  4558848
#define OFF_ABL  4567040
#define OFF_CAH  4575232
#define OFF_CAL  4583424
#define OFF_CBH  4591616
#define OFF_CBL  4593664
// end ~4.6 MB

// ---------------- fused: A*A (fp32 + hi/lo) and split A,B,C,D ----------------
__global__ void k_mm_conv(const float* __restrict__ A, const float* __restrict__ B,
                          const float* __restrict__ C, const float* __restrict__ D,
                          float* __restrict__ P, unsigned short* A2h, unsigned short* A2l,
                          unsigned short* Ah, unsigned short* Al,
                          unsigned short* Bh, unsigned short* Bl,
                          unsigned short* Ch, unsigned short* Cl,
                          unsigned short* Dh, unsigned short* Dl) {
  int gid = blockIdx.x * 256 + threadIdx.x;
  if (blockIdx.x < 64) {               // A^2
    int row = gid >> 7, col = gid & 127;
    const float* xr = A + row * 128;
    float a0 = 0.f, a1 = 0.f;
    #pragma unroll 8
    for (int k = 0; k < 128; k += 2) {
      a0 = fmaf(xr[k],     A[k * 128 + col],       a0);
      a1 = fmaf(xr[k + 1], A[(k + 1) * 128 + col], a1);
    }
    float acc = a0 + a1;
    P[gid] = acc;
    unsigned short h, l; split_trunc(acc, h, l);
    A2h[gid] = h; A2l[gid] = l;
  } else {                             // convert
    int idx = gid - 16384;
    unsigned short h, l;
    if (idx < 16384)      { split_trunc(A[idx], h, l); Ah[idx] = h; Al[idx] = l; }
    else if (idx < 20480) { int i = idx - 16384; split_trunc(B[i], h, l); Bh[i] = h; Bl[i] = l; }
    else if (idx < 24576) { int i = idx - 20480; split_trunc(C[i], h, l); Ch[i] = h; Cl[i] = l; }
    else if (idx < 25600) { int i = idx - 24576; split_trunc(D[i], h, l); Dh[i] = h; Dl[i] = l; }
  }
}

// ---------------- 128x128 fp32 matmul (powers chain) ----------------
__global__ void k_mm128(const float* __restrict__ X, const float* __restrict__ Y,
                        float* __restrict__ Z, unsigned short* Zh, unsigned short* Zl,
                        int writeBF) {
  int gid = blockIdx.x * 256 + threadIdx.x;
  int row = gid >> 7, col = gid & 127;
  const float* xr = X + row * 128;
  float a0 = 0.f, a1 = 0.f;
  #pragma unroll 8
  for (int k = 0; k < 128; k += 2) {
    a0 = fmaf(xr[k],     Y[k * 128 + col],       a0);
    a1 = fmaf(xr[k + 1], Y[(k + 1) * 128 + col], a1);
  }
  float acc = a0 + a1;
  Z[gid] = acc;
  if (writeBF) { unsigned short h, l; split_trunc(acc, h, l); Zh[gid] = h; Zl[gid] = l; }
}

// ---------------- AB = A*B [128x32], CA = C*A [32x128], CB = C*B [32x32] (hi/lo) ----------------
__global__ void k_misc(const float* __restrict__ A, const float* __restrict__ B,
                       const float* __restrict__ C,
                       unsigned short* ABh, unsigned short* ABl,
                       unsigned short* CAh, unsigned short* CAl,
                       unsigned short* CBh, unsigned short* CBl) {
  int gid = blockIdx.x * 256 + threadIdx.x;   // 36 blocks -> 9216
  float acc = 0.f;
  unsigned short h, l;
  if (gid < 4096) {                    // AB[nx][u]
    int row = gid >> 5, col = gid & 31;
    #pragma unroll 8
    for (int k = 0; k < 128; ++k) acc = fmaf(A[row * 128 + k], B[k * 32 + col], acc);
    split_trunc(acc, h, l); ABh[gid] = h; ABl[gid] = l;
  } else if (gid < 8192) {             // CA[ny][nx]
    int i = gid - 4096, row = i >> 7, col = i & 127;
    #pragma unroll 8
    for (int k = 0; k < 128; ++k) acc = fmaf(C[row * 128 + k], A[k * 128 + col], acc);
    split_trunc(acc, h, l); CAh[i] = h; CAl[i] = l;
  } else if (gid < 9216) {             // CB[ny][u]
    int i = gid - 8192, row = i >> 5, col = i & 31;
    #pragma unroll 8
    for (int k = 0; k < 128; ++k) acc = fmaf(C[row * 128 + k], B[k * 32 + col], acc);
    split_trunc(acc, h, l); CBh[i] = h; CBl[i] = l;
  }
}

// ---------------- pass 1: step-2 local chunk scans (x0=0) -> v_c = X_64 ----------------
__global__ __launch_bounds__(256, 1) void k_pass1(
    const float* __restrict__ d,
    const unsigned short* __restrict__ A2h, const unsigned short* __restrict__ A2l,
    const unsigned short* __restrict__ ABh, const unsigned short* __restrict__ ABl,
    const unsigned short* __restrict__ Bh,  const unsigned short* __restrict__ Bl,
    float* __restrict__ vout) {
  __shared__ unsigned short Xh[2][16][LPAD];
  __shared__ unsigned short Xl[2][16][LPAD];
  const int tid = threadIdx.x;
  const int w = tid >> 6, l = tid & 63, q = l >> 4, m = l & 15;
  const int g = blockIdx.x;

  s8v fA2h[2][4], fA2l[2][4], fABh[2], fABl[2], fBh[2], fBl[2];
  #pragma unroll
  for (int t2 = 0; t2 < 2; ++t2) {
    const int n = (2 * w + t2) * 16 + m;
    #pragma unroll
    for (int kt = 0; kt < 4; ++kt) {
      const int k0 = kt * 32 + q * 8;
      fA2h[t2][kt] = *(const s8v*)(A2h + n * 128 + k0);
      fA2l[t2][kt] = *(const s8v*)(A2l + n * 128 + k0);
    }
    fABh[t2] = *(const s8v*)(ABh + n * 32 + q * 8);
    fABl[t2] = *(const s8v*)(ABl + n * 32 + q * 8);
    fBh[t2]  = *(const s8v*)(Bh  + n * 32 + q * 8);
    fBl[t2]  = *(const s8v*)(Bl  + n * 32 + q * 8);
  }
  for (int i = tid; i < 16 * LPAD; i += 256) {
    ((unsigned short*)Xh[0])[i] = 0;
    ((unsigned short*)Xl[0])[i] = 0;
  }
  __syncthreads();

  const int ch = g * 16 + m, b = ch >> 6, chunk = ch & 63;
  const float* ubase = d + ((size_t)b * NN + chunk * 64) * NU + q * 8;

  f32x4 cu[4];
  cu[0] = *(const f32x4*)(ubase);      cu[1] = *(const f32x4*)(ubase + 4);
  cu[2] = *(const f32x4*)(ubase + 32); cu[3] = *(const f32x4*)(ubase + 36);

  f32x4 acc[2];
  #pragma unroll 2
  for (int r = 0; r < 32; ++r) {
    const int p = r & 1;
    f32x4 nu0 = cu[0], nu1 = cu[1], nu2 = cu[2], nu3 = cu[3];
    if (r < 31) {
      const float* up = ubase + (size_t)(2 * r + 2) * NU;
      nu0 = *(const f32x4*)up;        nu1 = *(const f32x4*)(up + 4);
      nu2 = *(const f32x4*)(up + 32); nu3 = *(const f32x4*)(up + 36);
    }
    s8v u0h, u0l, u1h, u1l;
    split8(cu[0], cu[1], u0h, u0l);
    split8(cu[2], cu[3], u1h, u1l);
    s8v fXh[4], fXl[4];
    #pragma unroll
    for (int kt = 0; kt < 4; ++kt) {
      fXh[kt] = *(const s8v*)&Xh[p][m][kt * 32 + q * 8];
      fXl[kt] = *(const s8v*)&Xl[p][m][kt * 32 + q * 8];
    }
    #pragma unroll
    for (int t2 = 0; t2 < 2; ++t2) {
      f32x4 a0 = {0.f,0.f,0.f,0.f}, a1 = {0.f,0.f,0.f,0.f}, a2 = {0.f,0.f,0.f,0.f};
      #pragma unroll
      for (int kt = 0; kt < 4; ++kt) a0 = mfma16(fXh[kt], fA2h[t2][kt], a0);
      a0 = mfma16(u0h, fABh[t2], a0);
      a0 = mfma16(u1h, fBh[t2],  a0);
      #pragma unroll
      for (int kt = 0; kt < 4; ++kt) a1 = mfma16(fXl[kt], fA2h[t2][kt], a1);
      a1 = mfma16(u0l, fABh[t2], a1);
      a1 = mfma16(u1l, fBh[t2],  a1);
      #pragma unroll
      for (int kt = 0; kt < 4; ++kt) a2 = mfma16(fXh[kt], fA2l[t2][kt], a2);
      a2 = mfma16(u0h, fABl[t2], a2);
      a2 = mfma16(u1h, fBl[t2],  a2);
      acc[t2] = a0 + a1 + a2;
    }
    if (r < 31) {
      #pragma unroll
      for (int t2 = 0; t2 < 2; ++t2) {
        const int col = (2 * w + t2) * 16 + m;
        #pragma unroll
        for (int rr = 0; rr < 4; ++rr) {
          unsigned short h, lo;
          split_trunc(acc[t2][rr], h, lo);
          Xh[1 - p][q * 4 + rr][col] = h;
          Xl[1 - p][q * 4 + rr][col] = lo;
        }
      }
      __syncthreads();
      cu[0] = nu0; cu[1] = nu1; cu[2] = nu2; cu[3] = nu3;
    }
  }
  // v = X_64 exact from accumulators
  #pragma unroll
  for (int t2 = 0; t2 < 2; ++t2) {
    const int col = (2 * w + t2) * 16 + m;
    #pragma unroll
    for (int rr = 0; rr < 4; ++rr) {
      const int row = g * 16 + q * 4 + rr;
      vout[(size_t)row * 128 + col] = acc[t2][rr];
    }
  }
}

// ---------------- carry: s_c = v_{c-1} (fp32 exact) + G v_{c-2} (hi/lo 3-term) ----------------
__global__ __launch_bounds__(256, 1) void k_carry(
    const unsigned short* __restrict__ Gh, const unsigned short* __restrict__ Gl,
    const float* __restrict__ v, float* __restrict__ sout) {
  const int tid = threadIdx.x;
  const int w = tid >> 6, l = tid & 63, q = l >> 4, m = l & 15;
  const int g = blockIdx.x;

  s8v fGh[2][4], fGl[2][4];
  #pragma unroll
  for (int t2 = 0; t2 < 2; ++t2) {
    const int n = (2 * w + t2) * 16 + m;
    #pragma unroll
    for (int kt = 0; kt < 4; ++kt) {
      const int k0 = kt * 32 + q * 8;
      fGh[t2][kt] = *(const s8v*)(Gh + n * 128 + k0);
      fGl[t2][kt] = *(const s8v*)(Gl + n * 128 + k0);
    }
  }
  const int chm = g * 16 + m, cm = chm & 63;
  const s8v zero = {0,0,0,0,0,0,0,0};
  s8v v2h[4], v2l[4];
  #pragma unroll
  for (int kt = 0; kt < 4; ++kt) {
    if (cm >= 2) {
      const float* vp = v + (size_t)(chm - 2) * 128 + kt * 32 + q * 8;
      split8(*(const f32x4*)vp, *(const f32x4*)(vp + 4), v2h[kt], v2l[kt]);
    } else { v2h[kt] = zero; v2l[kt] = zero; }
  }
  f32x4 acc[2];
  #pragma unroll
  for (int t2 = 0; t2 < 2; ++t2) {
    f32x4 a = {0.f,0.f,0.f,0.f};
    #pragma unroll
    for (int kt = 0; kt < 4; ++kt) {
      a = mfma16(v2h[kt], fGh[t2][kt], a);
      a = mfma16(v2l[kt], fGh[t2][kt], a);
      a = mfma16(v2h[kt], fGl[t2][kt], a);
    }
    acc[t2] = a;
  }
  #pragma unroll
  for (int t2 = 0; t2 < 2; ++t2) {
    const int col = (2 * w + t2) * 16 + m;
    #pragma unroll
    for (int rr = 0; rr < 4; ++rr) {
      const int chr = g * 16 + q * 4 + rr, cr = chr & 63;
      float sv = 0.f;
      if (cr >= 1) sv = acc[t2][rr] + v[(size_t)(chr - 1) * 128 + col];
      sout[(size_t)chr * 128 + col] = sv;
    }
  }
}

// ---------------- pass 2: step-2 re-scan, write x (exact fp32) and y ----------------
__global__ __launch_bounds__(256, 1) void k_pass2(
    const float* __restrict__ d, const float* __restrict__ s,
    const unsigned short* __restrict__ Ah,  const unsigned short* __restrict__ Al,
    const unsigned short* __restrict__ A2h, const unsigned short* __restrict__ A2l,
    const unsigned short* __restrict__ ABh, const unsigned short* __restrict__ ABl,
    const unsigned short* __restrict__ Bh,  const unsigned short* __restrict__ Bl,
    const unsigned short* __restrict__ Ch,  const unsigned short* __restrict__ Cl,
    const unsigned short* __restrict__ CAh, const unsigned short* __restrict__ CAl,
    const unsigned short* __restrict__ CBh, const unsigned short* __restrict__ CBl,
    const unsigned short* __restrict__ Dh,  const unsigned short* __restrict__ Dl,
    float* __restrict__ yout, float* __restrict__ xout) {
  __shared__ unsigned short Xh[2][16][LPAD];
  __shared__ unsigned short Xl[2][16][LPAD];
  const int tid = threadIdx.x;
  const int w = tid >> 6, l = tid & 63, q = l >> 4, m = l & 15;
  const int g = blockIdx.x;

  s8v fAh[2][4], fAl[2][4], fA2h[2][4], fA2l[2][4];
  s8v fABh[2], fABl[2], fBh[2], fBl[2];
  #pragma unroll
  for (int t2 = 0; t2 < 2; ++t2) {
    const int n = (2 * w + t2) * 16 + m;
    #pragma unroll
    for (int kt = 0; kt < 4; ++kt) {
      const int k0 = kt * 32 + q * 8;
      fAh[t2][kt]  = *(const s8v*)(Ah  + n * 128 + k0);
      fAl[t2][kt]  = *(const s8v*)(Al  + n * 128 + k0);
      fA2h[t2][kt] = *(const s8v*)(A2h + n * 128 + k0);
      fA2l[t2][kt] = *(const s8v*)(A2l + n * 128 + k0);
    }
    fABh[t2] = *(const s8v*)(ABh + n * 32 + q * 8);
    fABl[t2] = *(const s8v*)(ABl + n * 32 + q * 8);
    fBh[t2]  = *(const s8v*)(Bh  + n * 32 + q * 8);
    fBl[t2]  = *(const s8v*)(Bl  + n * 32 + q * 8);
  }
  s8v fCh[4] = {}, fCl[4] = {}, fCAh[4] = {}, fCAl[4] = {};
  s8v fCBh = {}, fCBl = {}, fDh = {}, fDl = {};
  if (w < 2) {
    const int o = w * 16 + m;
    #pragma unroll
    for (int kt = 0; kt < 4; ++kt) {
      const int k0 = kt * 32 + q * 8;
      fCh[kt]  = *(const s8v*)(Ch  + o * 128 + k0);
      fCl[kt]  = *(const s8v*)(Cl  + o * 128 + k0);
      fCAh[kt] = *(const s8v*)(CAh + o * 128 + k0);
      fCAl[kt] = *(const s8v*)(CAl + o * 128 + k0);
    }
    fCBh = *(const s8v*)(CBh + o * 32 + q * 8);
    fCBl = *(const s8v*)(CBl + o * 32 + q * 8);
    fDh  = *(const s8v*)(Dh  + o * 32 + q * 8);
    fDl  = *(const s8v*)(Dl  + o * 32 + q * 8);
  }

  // init: X_0 = s -> LDS buf0, and write x at j0 = chunk*64 (exact fp32 s)
  {
    const int lb = tid >> 4, i0 = (tid & 15) * 8;
    const int chS = g * 16 + lb, bS = chS >> 6, cS = chS & 63;
    const float* sp = s + (size_t)chS * 128 + i0;
    f32x4 s0 = *(const f32x4*)sp, s1 = *(const f32x4*)(sp + 4);
    s8v hh, ll;
    split8(s0, s1, hh, ll);
    *(s8v*)&Xh[0][lb][i0] = hh;
    *(s8v*)&Xl[0][lb][i0] = ll;
    float* xp = xout + ((size_t)bS * (NN + 1) + (size_t)cS * 64) * NX + i0;
    *(f32x4*)xp = s0;
    *(f32x4*)(xp + 4) = s1;
  }
  __syncthreads();

  const int ch = g * 16 + m, b = ch >> 6, chunk = ch & 63;
  const float* ubase = d + ((size_t)b * NN + chunk * 64) * NU + q * 8;

  // per-(t2,rr) output pointers
  float* xptr[2][4];
  bool xlast[2][4];   // write x at j=64 only for chunk 63
  float* yptr[4];
  #pragma unroll
  for (int t2 = 0; t2 < 2; ++t2) {
    const int col = (2 * w + t2) * 16 + m;
    #pragma unroll
    for (int rr = 0; rr < 4; ++rr) {
      const int chX = g * 16 + q * 4 + rr, bX = chX >> 6, cX = chX & 63;
      xptr[t2][rr] = xout + ((size_t)bX * (NN + 1) + (size_t)cX * 64 + 1) * NX + col;
      xlast[t2][rr] = (cX == 63);
    }
  }
  #pragma unroll
  for (int rr = 0; rr < 4; ++rr) {
    const int chY = g * 16 + q * 4 + rr, bY = chY >> 6, cY = chY & 63;
    yptr[rr] = yout + ((size_t)bY * NN + (size_t)cY * 64) * NY + w * 16 + m;
  }

  f32x4 cu[4];
  cu[0] = *(const f32x4*)(ubase);      cu[1] = *(const f32x4*)(ubase + 4);
  cu[2] = *(const f32x4*)(ubase + 32); cu[3] = *(const f32x4*)(ubase + 36);

  #pragma unroll 2
  for (int r = 0; r < 32; ++r) {
    const int p = r & 1;
    f32x4 nu0 = cu[0], nu1 = cu[1], nu2 = cu[2], nu3 = cu[3];
    if (r < 31) {
      const float* up = ubase + (size_t)(2 * r + 2) * NU;
      nu0 = *(const f32x4*)up;        nu1 = *(const f32x4*)(up + 4);
      nu2 = *(const f32x4*)(up + 32); nu3 = *(const f32x4*)(up + 36);
    }
    s8v u0h, u0l, u1h, u1l;
    split8(cu[0], cu[1], u0h, u0l);
    split8(cu[2], cu[3], u1h, u1l);
    s8v fXh[4], fXl[4];
    #pragma unroll
    for (int kt = 0; kt < 4; ++kt) {
      fXh[kt] = *(const s8v*)&Xh[p][m][kt * 32 + q * 8];
      fXl[kt] = *(const s8v*)&Xl[p][m][kt * 32 + q * 8];
    }

    // Y1 = A X + B u0  -> x_{2r+1} (exact fp32 from accs)
    f32x4 y1[2];
    #pragma unroll
    for (int t2 = 0; t2 < 2; ++t2) {
      f32x4 a0 = {0.f,0.f,0.f,0.f}, a1 = {0.f,0.f,0.f,0.f}, a2 = {0.f,0.f,0.f,0.f};
      #pragma unroll
      for (int kt = 0; kt < 4; ++kt) a0 = mfma16(fXh[kt], fAh[t2][kt], a0);
      a0 = mfma16(u0h, fBh[t2], a0);
      #pragma unroll
      for (int kt = 0; kt < 4; ++kt) a1 = mfma16(fXl[kt], fAh[t2][kt], a1);
      a1 = mfma16(u0l, fBh[t2], a1);
      #pragma unroll
      for (int kt = 0; kt < 4; ++kt) a2 = mfma16(fXh[kt], fAl[t2][kt], a2);
      a2 = mfma16(u0h, fBl[t2], a2);
      y1[t2] = a0 + a1 + a2;
    }
    // X2 = A^2 X + AB u0 + B u1
    f32x4 acc[2];
    #pragma unroll
    for (int t2 = 0; t2 < 2; ++t2) {
      f32x4 a0 = {0.f,0.f,0.f,0.f}, a1 = {0.f,0.f,0.f,0.f}, a2 = {0.f,0.f,0.f,0.f};
      #pragma unroll
      for (int kt = 0; kt < 4; ++kt) a0 = mfma16(fXh[kt], fA2h[t2][kt], a0);
      a0 = mfma16(u0h, fABh[t2], a0);
      a0 = mfma16(u1h, fBh[t2],  a0);
      #pragma unroll
      for (int kt = 0; kt < 4; ++kt) a1 = mfma16(fXl[kt], fA2h[t2][kt], a1);
      a1 = mfma16(u0l, fABh[t2], a1);
      a1 = mfma16(u1l, fBh[t2],  a1);
      #pragma unroll
      for (int kt = 0; kt < 4; ++kt) a2 = mfma16(fXh[kt], fA2l[t2][kt], a2);
      a2 = mfma16(u0h, fABl[t2], a2);
      a2 = mfma16(u1h, fBl[t2],  a2);
      acc[t2] = a0 + a1 + a2;
    }

    // x writes: odd j=2r+1 always; even j=2r+2 except j=64 for chunk<63
    #pragma unroll
    for (int t2 = 0; t2 < 2; ++t2) {
      #pragma unroll
      for (int rr = 0; rr < 4; ++rr) {
        *(xptr[t2][rr]) = y1[t2][rr];
        if (r < 31 || xlast[t2][rr]) *(xptr[t2][rr] + NX) = acc[t2][rr];
      }
    }

    // y_{2r} = C X + D u0 ; y_{2r+1} = CA X + CB u0 + D u1  (waves 0,1)
    if (w < 2) {
      f32x4 b0 = {0.f,0.f,0.f,0.f}, b1 = {0.f,0.f,0.f,0.f}, b2 = {0.f,0.f,0.f,0.f};
      #pragma unroll
      for (int kt = 0; kt < 4; ++kt) b0 = mfma16(fXh[kt], fCh[kt], b0);
      b0 = mfma16(u0h, fDh, b0);
      #pragma unroll
      for (int kt = 0; kt < 4; ++kt) b1 = mfma16(fXl[kt], fCh[kt], b1);
      b1 = mfma16(u0l, fDh, b1);
      #pragma unroll
      for (int kt = 0; kt < 4; ++kt) b2 = mfma16(fXh[kt], fCl[kt], b2);
      b2 = mfma16(u0h, fDl, b2);
      f32x4 y0 = b0 + b1 + b2;

      f32x4 c0 = {0.f,0.f,0.f,0.f}, c1 = {0.f,0.f,0.f,0.f}, c2 = {0.f,0.f,0.f,0.f};
      #pragma unroll
      for (int kt = 0; kt < 4; ++kt) c0 = mfma16(fXh[kt], fCAh[kt], c0);
      c0 = mfma16(u0h, fCBh, c0);
      c0 = mfma16(u1h, fDh,  c0);
      #pragma unroll
      for (int kt = 0; kt < 4; ++kt) c1 = mfma16(fXl[kt], fCAh[kt], c1);
      c1 = mfma16(u0l, fCBh, c1);
      c1 = mfma16(u1l, fDh,  c1);
      #pragma unroll
      for (int kt = 0; kt < 4; ++kt) c2 = mfma16(fXh[kt], fCAl[kt], c2);
      c2 = mfma16(u0h, fCBl, c2);
      c2 = mfma16(u1h, fDl,  c2);
      f32x4 yo = c0 + c1 + c2;

      #pragma unroll
      for (int rr = 0; rr < 4; ++rr) {
        *(yptr[rr]) = y0[rr];
        *(yptr[rr] + NY) = yo[rr];
      }
    }

    if (r < 31) {
      #pragma unroll
      for (int t2 = 0; t2 < 2; ++t2) {
        const int col = (2 * w + t2) * 16 + m;
        #pragma unroll
        for (int rr = 0; rr < 4; ++rr) {
          unsigned short h, lo;
          split_trunc(acc[t2][rr], h, lo);
          Xh[1 - p][q * 4 + rr][col] = h;
          Xl[1 - p][q * 4 + rr][col] = lo;
        }
      }
      __syncthreads();
      cu[0] = nu0; cu[1] = nu1; cu[2] = nu2; cu[3] = nu3;
      #pragma unroll
      for (int t2 = 0; t2 < 2; ++t2)
        #pragma unroll
        for (int rr = 0; rr < 4; ++rr) xptr[t2][rr] += 2 * NX;
      #pragma unroll
      for (int rr = 0; rr < 4; ++rr) yptr[rr] += 2 * NY;
    }
  }
}

// ---------------- launcher ----------------
extern "C" void kernel_launch(void* const* d_in, const int* in_sizes, int n_in,
                              void* d_out, int out_size, void* d_ws, size_t ws_size,
                              hipStream_t stream) {
  (void)in_sizes; (void)n_in; (void)out_size; (void)ws_size;
  const float* d = (const float*)d_in[0];
  const float* A = (const float*)d_in[1];
  const float* B = (const float*)d_in[2];
  const float* C = (const float*)d_in[3];
  const float* D = (const float*)d_in[4];

  char* ws = (char*)d_ws;
  unsigned short* Ah  = (unsigned short*)(ws + OFF_AH);
  unsigned short* Al  = (unsigned short*)(ws + OFF_AL);
  unsigned short* Bh  = (unsigned short*)(ws + OFF_BH);
  unsigned short* Bl  = (unsigned short*)(ws + OFF_BL);
  unsigned short* Chp = (unsigned short*)(ws + OFF_CH);
  unsigned short* Clp = (unsigned short*)(ws + OFF_CL);
  unsigned short* Dhp = (unsigned short*)(ws + OFF_DH);
  unsigned short* Dlp = (unsigned short*)(ws + OFF_DL);
  unsigned short* Gh  = (unsigned short*)(ws + OFF_GH);
  unsigned short* Gl  = (unsigned short*)(ws + OFF_GL);
  unsigned short* A2h = (unsigned short*)(ws + OFF_A2H);
  unsigned short* A2l = (unsigned short*)(ws + OFF_A2L);
  unsigned short* ABh = (unsigned short*)(ws + OFF_ABH);
  unsigned short* ABl = (unsigned short*)(ws + OFF_ABL);
  unsigned short* CAh = (unsigned short*)(ws + OFF_CAH);
  unsigned short* CAl = (unsigned short*)(ws + OFF_CAL);
  unsigned short* CBh = (unsigned short*)(ws + OFF_CBH);
  unsigned short* CBl = (unsigned short*)(ws + OFF_CBL);
  float* P0 = (float*)(ws + OFF_P0);
  float* P1 = (float*)(ws + OFF_P1);
  float* V  = (float*)(ws + OFF_V);
  float* S  = (float*)(ws + OFF_S);

  float* yout = (float*)d_out;
  float* xout = yout + (size_t)BATCH * NN * NY;

  k_mm_conv<<<164, 256, 0, stream>>>(A, B, C, D, P0, A2h, A2l,
                                     Ah, Al, Bh, Bl, Chp, Clp, Dhp, Dlp);   // A^2 + splits
  k_mm128<<<64, 256, 0, stream>>>(P0, P0, P1, nullptr, nullptr, 0);         // A^4
  k_mm128<<<64, 256, 0, stream>>>(P1, P1, P0, nullptr, nullptr, 0);         // A^8
  k_mm128<<<64, 256, 0, stream>>>(P0, P0, P1, nullptr, nullptr, 0);         // A^16
  k_mm128<<<64, 256, 0, stream>>>(P1, P1, P0, nullptr, nullptr, 0);         // A^32
  k_mm128<<<64, 256, 0, stream>>>(P0, P0, P1, Gh, Gl, 1);                   // A^64 -> G
  k_misc<<<36, 256, 0, stream>>>(A, B, C, ABh, ABl, CAh, CAl, CBh, CBl);

  k_pass1<<<256, 256, 0, stream>>>(d, A2h, A2l, ABh, ABl, Bh, Bl, V);
  k_carry<<<256, 256, 0, stream>>>(Gh, Gl, V, S);
  k_pass2<<<256, 256, 0, stream>>>(d, S, Ah, Al, A2h, A2l, ABh, ABl, Bh, Bl,
                                   Chp, Clp, CAh, CAl, CBh, CBl, Dhp, Dlp, yout, xout);
}